// Round 1
// baseline (36.415 us; speedup 1.0000x reference)
//
#include <hip/hip_runtime.h>
#include <math.h>

#define BLOCK 256
#define WAVES_PER_BLOCK 4
#define LL 50
#define DD 50
#define RR 3
#define CC 10

__global__ __launch_bounds__(BLOCK) void fused_combo_kernel(
    const int*   __restrict__ x,          // [B, L] int32
    const float* __restrict__ emb_mask,   // [B, L]
    const int*   __restrict__ combo_idx,  // [B, C, R] int32, values in [0, L)
    const float* __restrict__ emb_table,  // [VOCAB, D]
    const float* __restrict__ W,          // [1, R*D] = [150]
    const float* __restrict__ bvec,       // [1]
    float*       __restrict__ out,        // [B]
    int B)
{
    __shared__ int   s_used[WAVES_PER_BLOCK][LL];
    __shared__ int   s_cidx[WAVES_PER_BLOCK][CC * RR];
    __shared__ float s_d[WAVES_PER_BLOCK][RR][LL];

    const int tid  = threadIdx.x;
    const int w    = tid >> 6;       // wave id within block
    const int lane = tid & 63;
    const int b    = blockIdx.x * WAVES_PER_BLOCK + w;
    const bool active = (b < B);

    // Phase 1: mark which of the L rows are actually used by this sample's combos.
    if (active) {
        if (lane < LL) s_used[w][lane] = 0;
        if (lane < CC * RR) {
            int ci = combo_idx[b * (CC * RR) + lane];
            s_cidx[w][lane] = ci;
            s_used[w][ci] = 1;   // same-wave program order after the zeroing store
        }
    }
    __syncthreads();

    // Phase 2: lane l computes d_r[l] = mask * dot(emb_table[x[b][l]], w_r) for r=0..2
    if (active && lane < LL && s_used[w][lane]) {
        int   row = x[b * LL + lane];
        float m   = emb_mask[b * LL + lane];
        const float* p = emb_table + (size_t)row * DD;   // 8-byte aligned (200B rows)
        float d0 = 0.f, d1 = 0.f, d2 = 0.f;
        #pragma unroll
        for (int j = 0; j < DD / 2; ++j) {
            float2 v = *reinterpret_cast<const float2*>(p + 2 * j);
            // W indices are wave-uniform -> scalar loads
            d0 = fmaf(v.x, W[          2 * j], fmaf(v.y, W[          2 * j + 1], d0));
            d1 = fmaf(v.x, W[    DD  + 2 * j], fmaf(v.y, W[    DD  + 2 * j + 1], d1));
            d2 = fmaf(v.x, W[2 * DD  + 2 * j], fmaf(v.y, W[2 * DD  + 2 * j + 1], d2));
        }
        s_d[w][0][lane] = d0 * m;
        s_d[w][1][lane] = d1 * m;
        s_d[w][2][lane] = d2 * m;
    }
    __syncthreads();

    // Phase 3: lanes 0..9 each evaluate one combo; wave-reduce; lane 0 writes.
    float v = 0.f;
    if (active && lane < CC) {
        int i0 = s_cidx[w][lane * RR + 0];
        int i1 = s_cidx[w][lane * RR + 1];
        int i2 = s_cidx[w][lane * RR + 2];
        float s = s_d[w][0][i0] + s_d[w][1][i1] + s_d[w][2][i2] + bvec[0];
        v = 1.0f / (1.0f + __expf(-s));
    }
    #pragma unroll
    for (int off = 32; off > 0; off >>= 1)
        v += __shfl_down(v, off);
    if (active && lane == 0)
        out[b] = v;
}

extern "C" void kernel_launch(void* const* d_in, const int* in_sizes, int n_in,
                              void* d_out, int out_size, void* d_ws, size_t ws_size,
                              hipStream_t stream) {
    const int*   x         = (const int*)d_in[0];
    const float* emb_mask  = (const float*)d_in[1];
    const int*   combo_idx = (const int*)d_in[2];
    // d_in[3] = step (unused)
    const float* emb_table = (const float*)d_in[4];
    const float* W         = (const float*)d_in[5];
    const float* bvec      = (const float*)d_in[6];
    float*       out       = (float*)d_out;

    const int B = out_size;  // OUT == 1
    const int grid = (B + WAVES_PER_BLOCK - 1) / WAVES_PER_BLOCK;
    fused_combo_kernel<<<grid, BLOCK, 0, stream>>>(
        x, emb_mask, combo_idx, emb_table, W, bvec, out, B);
}

// Round 2
// 24.668 us; speedup vs baseline: 1.4762x; 1.4762x over previous
//
#include <hip/hip_runtime.h>
#include <math.h>

#define BLOCK 256
#define WAVES_PER_BLOCK 4
#define LL 50
#define DD 50
#define RR 3
#define CC 10

// Kernel 1: d_r[v] = dot(emb_table[v], W[r*D .. r*D+D)) for r = 0..2.
// Streaming 20 MB read, 1.6 MB write. One thread per vocab row.
__global__ __launch_bounds__(256) void precompute_dots_kernel(
    const float* __restrict__ emb_table,  // [VOCAB, D]
    const float* __restrict__ W,          // [R*D] = [150]
    float4*      __restrict__ dtab,       // [VOCAB]
    int vocab)
{
    int v = blockIdx.x * 256 + threadIdx.x;
    if (v >= vocab) return;
    const float* p = emb_table + (size_t)v * DD;   // 200B rows: 8B aligned
    float d0 = 0.f, d1 = 0.f, d2 = 0.f;
    #pragma unroll
    for (int j = 0; j < DD / 2; ++j) {
        float2 e = *reinterpret_cast<const float2*>(p + 2 * j);
        d0 = fmaf(e.x, W[          2 * j], fmaf(e.y, W[          2 * j + 1], d0));
        d1 = fmaf(e.x, W[    DD  + 2 * j], fmaf(e.y, W[    DD  + 2 * j + 1], d1));
        d2 = fmaf(e.x, W[2 * DD  + 2 * j], fmaf(e.y, W[2 * DD  + 2 * j + 1], d2));
    }
    dtab[v] = make_float4(d0, d1, d2, 0.f);
}

// Kernel 2: per sample, gather precomputed dots, apply mask, evaluate the
// C combos (3 LDS lookups + sigmoid each), sum. One wave per sample.
__global__ __launch_bounds__(BLOCK) void fused_combo_kernel(
    const int*    __restrict__ x,          // [B, L] int32
    const float*  __restrict__ emb_mask,   // [B, L]
    const int*    __restrict__ combo_idx,  // [B, C, R] int32, values in [0, L)
    const float4* __restrict__ dtab,       // [VOCAB] precomputed dots
    const float*  __restrict__ bvec,       // [1]
    float*        __restrict__ out,        // [B]
    int B)
{
    __shared__ float s_d[WAVES_PER_BLOCK][RR][LL];
    __shared__ int   s_cidx[WAVES_PER_BLOCK][CC * RR];

    const int tid  = threadIdx.x;
    const int w    = tid >> 6;
    const int lane = tid & 63;
    const int b    = blockIdx.x * WAVES_PER_BLOCK + w;
    const bool active = (b < B);

    if (active) {
        if (lane < LL) {
            int   row = x[b * LL + lane];
            float m   = emb_mask[b * LL + lane];
            float4 d  = dtab[row];              // 16B gather, L2-resident 1.6MB
            s_d[w][0][lane] = d.x * m;
            s_d[w][1][lane] = d.y * m;
            s_d[w][2][lane] = d.z * m;
        }
        if (lane < CC * RR) {
            s_cidx[w][lane] = combo_idx[b * (CC * RR) + lane];
        }
    }
    __syncthreads();

    float v = 0.f;
    if (active && lane < CC) {
        int i0 = s_cidx[w][lane * RR + 0];
        int i1 = s_cidx[w][lane * RR + 1];
        int i2 = s_cidx[w][lane * RR + 2];
        float s = s_d[w][0][i0] + s_d[w][1][i1] + s_d[w][2][i2] + bvec[0];
        v = 1.0f / (1.0f + __expf(-s));
    }
    #pragma unroll
    for (int off = 32; off > 0; off >>= 1)
        v += __shfl_down(v, off);
    if (active && lane == 0)
        out[b] = v;
}

extern "C" void kernel_launch(void* const* d_in, const int* in_sizes, int n_in,
                              void* d_out, int out_size, void* d_ws, size_t ws_size,
                              hipStream_t stream) {
    const int*   x         = (const int*)d_in[0];
    const float* emb_mask  = (const float*)d_in[1];
    const int*   combo_idx = (const int*)d_in[2];
    // d_in[3] = step (unused)
    const float* emb_table = (const float*)d_in[4];
    const float* W         = (const float*)d_in[5];
    const float* bvec      = (const float*)d_in[6];
    float*       out       = (float*)d_out;

    const int B     = out_size;            // OUT == 1
    const int vocab = in_sizes[4] / DD;    // emb_table is [VOCAB, D]

    float4* dtab = (float4*)d_ws;          // 16 * VOCAB bytes = 1.6 MB scratch

    precompute_dots_kernel<<<(vocab + 255) / 256, 256, 0, stream>>>(
        emb_table, W, dtab, vocab);

    const int grid = (B + WAVES_PER_BLOCK - 1) / WAVES_PER_BLOCK;
    fused_combo_kernel<<<grid, BLOCK, 0, stream>>>(
        x, emb_mask, combo_idx, dtab, bvec, out, B);
}